// Round 1
// baseline (296.006 us; speedup 1.0000x reference)
//
#include <hip/hip_runtime.h>
#include <hip/hip_bf16.h>
#include <cstdint>

// ---------------------------------------------------------------------------
// LocalWindowTransformer: windowed MHA, B=4 L=4096 H=1024 NH=16 hd=64 P=128
// R6: both GEMM K-loops (qkv phase-1 and gemm_out) converted from the
//     drain-0 2-barrier structure (m97 ceiling, ~39% peak) to the T3+T4
//     counted-vmcnt depth-1 pipeline:
//       BK 64->32, double-buffered staging (SAME LDS footprint: qkv 53248B
//       -> 3 blocks/CU kept; gemm_out 48KB -> 2 blocks/CU kept),
//       raw s_barrier + s_waitcnt vmcnt(5|6) (never 0 except last tile),
//       setprio(1) around the MFMA cluster, sched_barrier(0) fences.
//     Next tile's global_load_lds stay in flight across both barriers;
//     latency hides under the MFMA cluster. k-accumulation order unchanged.
// MFMA 16x16x32 bf16 layouts (HW-verified per guide):
//   A-frag: lane holds A[m=lane&15][k=(lane>>4)*8+j], j=0..7
//   B-frag: lane holds B_hw[k=(lane>>4)*8+j][n=lane&15]
//   C/D   : reg r holds C[row=(lane>>4)*4+r][col=lane&15]
// BK=32 swizzled staging: row r (32 elems, 4 chunks of 8) stores chunk
//   (p ^ (r&3)) at position p; fragment read addr = r*32 + ((q4^(r&3))*8).
// ---------------------------------------------------------------------------

typedef __bf16 bf16_t;
typedef __bf16 bf16x8 __attribute__((ext_vector_type(8)));
typedef __bf16 bf16x4 __attribute__((ext_vector_type(4)));
typedef float  floatx4 __attribute__((ext_vector_type(4)));

#define MFMA_16x16x32(A, B, C) __builtin_amdgcn_mfma_f32_16x16x32_bf16(A, B, C, 0, 0, 0)

// async global->LDS, 16B per lane; LDS dest = wave-uniform base + lane*16
__device__ __forceinline__ void gld_lds16(const bf16_t* g, bf16_t* l) {
  __builtin_amdgcn_global_load_lds(
      (__attribute__((address_space(1))) void*)(void*)(g),
      (__attribute__((address_space(3))) void*)(l), 16, 0, 0);
}

__device__ __forceinline__ void cvt8(const float* __restrict__ s,
                                     bf16_t* __restrict__ d) {
  float4 a = ((const float4*)s)[0];
  float4 b = ((const float4*)s)[1];
  bf16x8 o;
  o[0] = (bf16_t)a.x; o[1] = (bf16_t)a.y; o[2] = (bf16_t)a.z; o[3] = (bf16_t)a.w;
  o[4] = (bf16_t)b.x; o[5] = (bf16_t)b.y; o[6] = (bf16_t)b.z; o[7] = (bf16_t)b.w;
  *(bf16x8*)d = o;
}

// ---------------------------------------------------------------------------
// One fused conversion dispatch, 8-elem chunks (unchanged from R5):
//   [0, 2097152)              x    [16384,1024] -> xb
//   [2097152, 2228224)        Wout [1024,1024]  -> Woutb
//   [2228224, 2621440)        Win  [3072,1024]  -> Wpk (head-packed repack)
__global__ void cvt_all(const float* __restrict__ x,
                        const float* __restrict__ Win,
                        const float* __restrict__ Wout,
                        bf16_t* __restrict__ xb,
                        bf16_t* __restrict__ Wpk,
                        bf16_t* __restrict__ Woutb) {
  const int idx = blockIdx.x * 256 + threadIdx.x;
  if (idx < 2097152) {
    cvt8(x + (size_t)idx * 8, xb + (size_t)idx * 8);
  } else if (idx < 2228224) {
    const int i = idx - 2097152;
    cvt8(Wout + (size_t)i * 8, Woutb + (size_t)i * 8);
  } else {
    const int c = idx - 2228224;          // 0..393215
    const int dr = c >> 7, i = c & 127;   // packed row, chunk-in-row
    const int head = dr / 192, s = dr - head * 192;
    const int src = (s < 64) ? head * 64 + s
                  : (s < 128) ? 1024 + head * 64 + (s - 64)
                              : 2048 + head * 64 + (s - 128);
    cvt8(Win + (size_t)src * 1024 + i * 8, Wpk + (size_t)dr * 1024 + i * 8);
  }
}

// ---------------------------------------------------------------------------
// Out-projection GEMM: BM=128, BN=256, BK=32 double-buffered pipeline.
// grid(4,128)=512 blocks = exactly 2/CU (one round). LDS 2x24KB = 48KB.
// Wave tile 64x128: acc[4][8]. 6 gld_lds per stage -> vmcnt(6) steady-state.
__global__ __launch_bounds__(256, 2) void gemm_out(
    const bf16_t* __restrict__ A, const bf16_t* __restrict__ Bm,
    const float* __restrict__ bias, float* __restrict__ C,
    int M, int N, int K) {
  __shared__ __align__(16) bf16_t smem[2][128 * 32 + 256 * 32];  // 2 x 24 KB
  const int tid  = threadIdx.x;
  const int lane = tid & 63;
  const int wave = tid >> 6;
  const int n16  = lane & 15;
  const int q4   = lane >> 4;
  const int wm   = (wave >> 1) * 64;
  const int wn   = (wave & 1) * 128;
  const int m0   = blockIdx.y * 128;
  const int n0   = blockIdx.x * 256;

  floatx4 acc[4][8] = {};

#define GO_STAGE(BUF, K0)                                                   \
  {                                                                         \
    bf16_t* Ad = smem[BUF];                                                 \
    bf16_t* Bd = smem[BUF] + 128 * 32;                                      \
    _Pragma("unroll")                                                       \
    for (int it = 0; it < 2; ++it) {  /* A: 512 chunks of 8 */              \
      const int ch = it * 256 + tid;                                        \
      const int r  = ch >> 2, c8 = (ch & 3) ^ (r & 3);                      \
      gld_lds16(A + (size_t)(m0 + r) * K + (K0) + c8 * 8,                   \
                Ad + (it * 256 + wave * 64) * 8);                           \
    }                                                                       \
    _Pragma("unroll")                                                       \
    for (int it = 0; it < 4; ++it) {  /* B: 1024 chunks of 8 */             \
      const int ch = it * 256 + tid;                                        \
      const int r  = ch >> 2, c8 = (ch & 3) ^ (r & 3);                      \
      gld_lds16(Bm + (size_t)(n0 + r) * K + (K0) + c8 * 8,                  \
                Bd + (it * 256 + wave * 64) * 8);                           \
    }                                                                       \
  }

#define GO_ITER(T, BUF)                                                     \
  {                                                                         \
    if ((T) < 31) { asm volatile("s_waitcnt vmcnt(6)" ::: "memory"); }      \
    else          { asm volatile("s_waitcnt vmcnt(0)" ::: "memory"); }      \
    __builtin_amdgcn_s_barrier();                                           \
    __builtin_amdgcn_sched_barrier(0);                                      \
    const bf16_t* As_ = smem[BUF];                                          \
    const bf16_t* Bs_ = smem[BUF] + 128 * 32;                               \
    bf16x8 af[4], bfr[8];                                                   \
    _Pragma("unroll")                                                       \
    for (int i = 0; i < 4; ++i) {                                           \
      const int row = wm + i * 16 + n16;                                    \
      af[i] = *(const bf16x8*)&As_[row * 32 + ((q4 ^ (row & 3)) * 8)];      \
    }                                                                       \
    _Pragma("unroll")                                                       \
    for (int j = 0; j < 8; ++j) {                                           \
      const int row = wn + j * 16 + n16;                                    \
      bfr[j] = *(const bf16x8*)&Bs_[row * 32 + ((q4 ^ (row & 3)) * 8)];     \
    }                                                                       \
    __builtin_amdgcn_s_setprio(1);                                          \
    _Pragma("unroll")                                                       \
    for (int i = 0; i < 4; ++i)                                             \
      _Pragma("unroll")                                                     \
      for (int j = 0; j < 8; ++j)                                           \
        acc[i][j] = MFMA_16x16x32(af[i], bfr[j], acc[i][j]);                \
    __builtin_amdgcn_s_setprio(0);                                          \
    asm volatile("s_waitcnt lgkmcnt(0)" ::: "memory");                      \
    __builtin_amdgcn_s_barrier();                                           \
    __builtin_amdgcn_sched_barrier(0);                                      \
    if ((T) + 2 < 32) GO_STAGE(BUF, ((T) + 2) * 32)                         \
  }

  GO_STAGE(0, 0)
  GO_STAGE(1, 32)
  for (int t = 0; t < 32; t += 2) {
    GO_ITER(t, 0)
    GO_ITER(t + 1, 1)
  }
#undef GO_ITER
#undef GO_STAGE

#pragma unroll
  for (int i = 0; i < 4; ++i)
#pragma unroll
    for (int j = 0; j < 8; ++j) {
      const int col = n0 + wn + j * 16 + n16;
      const float b = bias[col];
#pragma unroll
      for (int r = 0; r < 4; ++r) {
        const int row = m0 + wm + i * 16 + q4 * 4 + r;
        C[(size_t)row * N + col] = acc[i][j][r] + b;
      }
    }
}

// ---------------------------------------------------------------------------
// Fused QKV-projection + windowed attention.
// Phase 1 now BK=32 double-buffered counted-vmcnt pipeline; staging dbuf
// [0,40960B) aliases the attention region, total LDS unchanged at 53248 B
// -> 3 blocks/CU kept. 5 gld_lds per stage -> vmcnt(5) steady-state.
// Phase 2 (S=qk^T, softmax, PV) unchanged from R4/R5.
__global__ __launch_bounds__(256, 3) void qkv_attn(
    const bf16_t* __restrict__ X,    // [16384,1024]
    const bf16_t* __restrict__ Wpk,  // [16][192][1024]
    const float* __restrict__ bin,   // [3072]
    bf16_t* __restrict__ o)          // [16384,1024] merged heads
{
  __shared__ __align__(16) bf16_t smem[26624];  // 53248 B
  // staging: buf b at smem + b*10240: Xs [128][32] (4096), Ws [192][32] (6144)
  bf16_t* qs  = smem;                // [128][72] (aliases staging, post-barrier)
  bf16_t* ks  = smem + 9216;         // [128][72]
  bf16_t* vsT = smem + 18432;        // [64][128] XOR-swizzled
  bf16_t* Ps  = smem;                // [128][136] = 17408 <= 18432 (qs+ks)

  const int wid  = blockIdx.x;       // window 0..127 (XCD-affine: wid%8)
  const int h    = blockIdx.y;       // head 0..15
  const int tid  = threadIdx.x;
  const int lane = tid & 63;
  const int wave = tid >> 6;
  const int n16  = lane & 15;
  const int q4   = lane >> 4;
  const int wm   = (wave >> 1) * 64;   // wave M-offset (0/64)
  const int wn   = (wave & 1) * 96;    // wave N-offset (0/96)

  const bf16_t* Xg = X + (size_t)wid * 128 * 1024;
  const bf16_t* Wg = Wpk + (size_t)h * 192 * 1024;

  // ---- phase 1: qkv = x @ W^T   (M=128, N=192, K=1024, BK=32, dbuf pipeline)
  floatx4 acc[4][6] = {};

#define QKV_STAGE(BUF, K0)                                                  \
  {                                                                         \
    bf16_t* Xd = smem + (BUF) * 10240;                                      \
    bf16_t* Wd = Xd + 4096;                                                 \
    _Pragma("unroll")                                                       \
    for (int it = 0; it < 2; ++it) {  /* X: 512 chunks of 8 */              \
      const int ch = it * 256 + tid;                                        \
      const int r  = ch >> 2, c8 = (ch & 3) ^ (r & 3);                      \
      gld_lds16(Xg + (size_t)r * 1024 + (K0) + c8 * 8,                      \
                Xd + (it * 256 + wave * 64) * 8);                           \
    }                                                                       \
    _Pragma("unroll")                                                       \
    for (int it = 0; it < 3; ++it) {  /* W: 768 chunks of 8 */              \
      const int ch = it * 256 + tid;                                        \
      const int r  = ch >> 2, c8 = (ch & 3) ^ (r & 3);                      \
      gld_lds16(Wg + (size_t)r * 1024 + (K0) + c8 * 8,                      \
                Wd + (it * 256 + wave * 64) * 8);                           \
    }                                                                       \
  }

#define QKV_ITER(T, BUF)                                                    \
  {                                                                         \
    if ((T) < 31) { asm volatile("s_waitcnt vmcnt(5)" ::: "memory"); }      \
    else          { asm volatile("s_waitcnt vmcnt(0)" ::: "memory"); }      \
    __builtin_amdgcn_s_barrier();                                           \
    __builtin_amdgcn_sched_barrier(0);                                      \
    const bf16_t* Xb = smem + (BUF) * 10240;                                \
    const bf16_t* Wb = Xb + 4096;                                           \
    bf16x8 af[4], bfr[6];                                                   \
    _Pragma("unroll")                                                       \
    for (int i = 0; i < 4; ++i) {                                           \
      const int row = wm + i * 16 + n16;                                    \
      af[i] = *(const bf16x8*)&Xb[row * 32 + ((q4 ^ (row & 3)) * 8)];       \
    }                                                                       \
    _Pragma("unroll")                                                       \
    for (int j = 0; j < 6; ++j) {                                           \
      const int row = wn + j * 16 + n16;                                    \
      bfr[j] = *(const bf16x8*)&Wb[row * 32 + ((q4 ^ (row & 3)) * 8)];      \
    }                                                                       \
    __builtin_amdgcn_s_setprio(1);                                          \
    _Pragma("unroll")                                                       \
    for (int i = 0; i < 4; ++i)                                             \
      _Pragma("unroll")                                                     \
      for (int j = 0; j < 6; ++j)                                           \
        acc[i][j] = MFMA_16x16x32(af[i], bfr[j], acc[i][j]);                \
    __builtin_amdgcn_s_setprio(0);                                          \
    asm volatile("s_waitcnt lgkmcnt(0)" ::: "memory");                      \
    __builtin_amdgcn_s_barrier();                                           \
    __builtin_amdgcn_sched_barrier(0);                                      \
    if ((T) + 2 < 32) QKV_STAGE(BUF, ((T) + 2) * 32)                        \
  }

  QKV_STAGE(0, 0)
  QKV_STAGE(1, 32)
  for (int t = 0; t < 32; t += 2) {
    QKV_ITER(t, 0)
    QKV_ITER(t + 1, 1)
  }
#undef QKV_ITER
#undef QKV_STAGE
  // final in-loop barrier: staging dead, all reads done -> qs/ks/vsT may alias

  // ---- epilogue: scatter acc -> qs (scaled), ks, vsT (swizzled transpose)
#pragma unroll
  for (int j = 0; j < 6; ++j) {
    const int base = wn + j * 16;   // wave-uniform
    const int col  = base + n16;    // 0..191
    const int gb = (base < 64) ? h * 64 + col
                 : (base < 128) ? 1024 + h * 64 + (col - 64)
                                : 2048 + h * 64 + (col - 128);
    const float bias = bin[gb];
#pragma unroll
    for (int i = 0; i < 4; ++i) {
      const int row0 = wm + i * 16 + q4 * 4;
      if (base < 64) {        // q, fold softmax scale 1/sqrt(64)
#pragma unroll
        for (int r = 0; r < 4; ++r)
          qs[(row0 + r) * 72 + col] = (bf16_t)((acc[i][j][r] + bias) * 0.125f);
      } else if (base < 128) {  // k
#pragma unroll
        for (int r = 0; r < 4; ++r)
          ks[(row0 + r) * 72 + (col - 64)] = (bf16_t)(acc[i][j][r] + bias);
      } else {                  // v -> transposed [dim][token], swizzled
        bf16x4 pv;
#pragma unroll
        for (int r = 0; r < 4; ++r) pv[r] = (bf16_t)(acc[i][j][r] + bias);
        const int d = col - 128;          // dim 0..63; d&15 == n16
        const int c8 = row0 >> 3, pos = row0 & 7;
        *(bf16x4*)&vsT[d * 128 + ((c8 ^ n16) << 3) + pos] = pv;
      }
    }
  }
  __syncthreads();

  // ---- S = q k^T  (wave w owns S rows [32w, 32w+32), K=64)
  floatx4 sacc[2][8] = {};
#pragma unroll
  for (int ks0 = 0; ks0 < 2; ++ks0) {
    bf16x8 aq[2];
#pragma unroll
    for (int i = 0; i < 2; ++i)
      aq[i] = *(const bf16x8*)&qs[(wave * 32 + i * 16 + n16) * 72 + ks0 * 32 + q4 * 8];
#pragma unroll
    for (int j = 0; j < 8; ++j) {
      bf16x8 bk = *(const bf16x8*)&ks[(j * 16 + n16) * 72 + ks0 * 32 + q4 * 8];
      sacc[0][j] = MFMA_16x16x32(aq[0], bk, sacc[0][j]);
      sacc[1][j] = MFMA_16x16x32(aq[1], bk, sacc[1][j]);
    }
  }
  __syncthreads();  // q/k reads done; Ps may overwrite their LDS

  // ---- softmax: no max-sub (logits bounded), P unnormalized, defer 1/sum
  float invs[2][4];
#pragma unroll
  for (int i = 0; i < 2; ++i) {
#pragma unroll
    for (int r = 0; r < 4; ++r) {
      float vals[8];
      float s = 0.f;
#pragma unroll
      for (int j = 0; j < 8; ++j) {
        vals[j] = __expf(sacc[i][j][r]);
        s += vals[j];
      }
      for (int m = 1; m < 16; m <<= 1) s += __shfl_xor(s, m, 64);
      invs[i][r] = 1.0f / s;
      const int prow = wave * 32 + i * 16 + q4 * 4 + r;
#pragma unroll
      for (int j = 0; j < 8; ++j)
        Ps[prow * 136 + j * 16 + n16] = (bf16_t)vals[j];
    }
  }
  __syncthreads();

  // ---- O = P V  (K=128; both operands via ds_read_b128)
  floatx4 oacc[2][4] = {};
#pragma unroll
  for (int kk = 0; kk < 4; ++kk) {
    bf16x8 ap[2];
#pragma unroll
    for (int i = 0; i < 2; ++i)
      ap[i] = *(const bf16x8*)&Ps[(wave * 32 + i * 16 + n16) * 136 + kk * 32 + q4 * 8];
#pragma unroll
    for (int j = 0; j < 4; ++j) {
      const int d = j * 16 + n16;
      bf16x8 bv = *(const bf16x8*)&vsT[d * 128 + (((kk * 4 + q4) ^ n16) << 3)];
      oacc[0][j] = MFMA_16x16x32(ap[0], bv, oacc[0][j]);
      oacc[1][j] = MFMA_16x16x32(ap[1], bv, oacc[1][j]);
    }
  }

  // ---- write o slice (scaled by 1/rowsum), merged-head layout [tok][h*64+d]
  bf16_t* go = o + (size_t)wid * 128 * 1024 + h * 64;
#pragma unroll
  for (int i = 0; i < 2; ++i)
#pragma unroll
    for (int j = 0; j < 4; ++j)
#pragma unroll
      for (int r = 0; r < 4; ++r) {
        const int row = wave * 32 + i * 16 + q4 * 4 + r;
        go[(size_t)row * 1024 + j * 16 + n16] = (bf16_t)(oacc[i][j][r] * invs[i][r]);
      }
}

// ---------------------------------------------------------------------------
extern "C" void kernel_launch(void* const* d_in, const int* in_sizes, int n_in,
                              void* d_out, int out_size, void* d_ws, size_t ws_size,
                              hipStream_t stream) {
  const float* x    = (const float*)d_in[0];
  const float* Win  = (const float*)d_in[1];   // [3072,1024]
  const float* bin  = (const float*)d_in[2];   // [3072]
  const float* Wout = (const float*)d_in[3];   // [1024,1024]
  const float* bout = (const float*)d_in[4];   // [1024]
  float* out = (float*)d_out;

  const size_t M = 16384, H = 1024, H3 = 3072;

  // workspace layout (~72 MB): xb | Wpk | Woutb | ob
  bf16_t* xb    = (bf16_t*)d_ws;        // M*H
  bf16_t* Wpk   = xb + M * H;           // H3*H (head-packed)
  bf16_t* Woutb = Wpk + H3 * H;         // H*H
  bf16_t* ob    = Woutb + H * H;        // M*H

  // one fused conversion dispatch: 2,621,440 8-elem chunks / 256 = 10240 blocks
  cvt_all<<<dim3(10240), 256, 0, stream>>>(x, Win, Wout, xb, Wpk, Woutb);

  // grid: window-major -> linear id = wid + 128*h -> window pins to XCD wid%8,
  // all 16 heads of a window share that XCD's L2 copy of X.
  qkv_attn<<<dim3(128, 16), 256, 0, stream>>>(xb, Wpk, bin, ob);

  // 512 blocks = one full dispatch round at 2/CU; XCD id%8 pins one B-tile.
  gemm_out<<<dim3((unsigned)(H / 256), (unsigned)(M / 128)), 256, 0, stream>>>(
      ob, Woutb, bout, out, (int)M, (int)H, (int)H);
}

// Round 2
// 291.011 us; speedup vs baseline: 1.0172x; 1.0172x over previous
//
#include <hip/hip_runtime.h>
#include <hip/hip_bf16.h>
#include <cstdint>

// ---------------------------------------------------------------------------
// LocalWindowTransformer: windowed MHA, B=4 L=4096 H=1024 NH=16 hd=64 P=128
// R7: R6's counted-vmcnt pipeline was correct but its BK=32 swizzle f(r)=r&3
//     caused 2-way bank conflicts on every fragment read (SQ_LDS_BANK_CONFLICT
//     1.18M -> 11.67M). With 64B rows the bank group is 4*(r&1)+chunk; an
//     octet of lanes (8 consecutive rows, fixed q4) needs all 8 groups
//     distinct. f(r)=(r>>1)&3 achieves that: group = 4*(r&1)+(q4^((r>>1)&3))
//     is a bijection over the octet. Write side pre-swizzles the global
//     source with the same involution; accumulation order unchanged.
// MFMA 16x16x32 bf16 layouts (HW-verified per guide):
//   A-frag: lane holds A[m=lane&15][k=(lane>>4)*8+j], j=0..7
//   B-frag: lane holds B_hw[k=(lane>>4)*8+j][n=lane&15]
//   C/D   : reg r holds C[row=(lane>>4)*4+r][col=lane&15]
// BK=32 swizzled staging: row r (32 elems, 4 chunks of 8) stores global
//   chunk (p ^ ((r>>1)&3)) at position p; read addr = r*32 + ((q4^((r>>1)&3))*8).
// ---------------------------------------------------------------------------

typedef __bf16 bf16_t;
typedef __bf16 bf16x8 __attribute__((ext_vector_type(8)));
typedef __bf16 bf16x4 __attribute__((ext_vector_type(4)));
typedef float  floatx4 __attribute__((ext_vector_type(4)));

#define MFMA_16x16x32(A, B, C) __builtin_amdgcn_mfma_f32_16x16x32_bf16(A, B, C, 0, 0, 0)

// async global->LDS, 16B per lane; LDS dest = wave-uniform base + lane*16
__device__ __forceinline__ void gld_lds16(const bf16_t* g, bf16_t* l) {
  __builtin_amdgcn_global_load_lds(
      (__attribute__((address_space(1))) void*)(void*)(g),
      (__attribute__((address_space(3))) void*)(l), 16, 0, 0);
}

__device__ __forceinline__ void cvt8(const float* __restrict__ s,
                                     bf16_t* __restrict__ d) {
  float4 a = ((const float4*)s)[0];
  float4 b = ((const float4*)s)[1];
  bf16x8 o;
  o[0] = (bf16_t)a.x; o[1] = (bf16_t)a.y; o[2] = (bf16_t)a.z; o[3] = (bf16_t)a.w;
  o[4] = (bf16_t)b.x; o[5] = (bf16_t)b.y; o[6] = (bf16_t)b.z; o[7] = (bf16_t)b.w;
  *(bf16x8*)d = o;
}

// ---------------------------------------------------------------------------
// One fused conversion dispatch, 8-elem chunks (unchanged):
//   [0, 2097152)              x    [16384,1024] -> xb
//   [2097152, 2228224)        Wout [1024,1024]  -> Woutb
//   [2228224, 2621440)        Win  [3072,1024]  -> Wpk (head-packed repack)
__global__ void cvt_all(const float* __restrict__ x,
                        const float* __restrict__ Win,
                        const float* __restrict__ Wout,
                        bf16_t* __restrict__ xb,
                        bf16_t* __restrict__ Wpk,
                        bf16_t* __restrict__ Woutb) {
  const int idx = blockIdx.x * 256 + threadIdx.x;
  if (idx < 2097152) {
    cvt8(x + (size_t)idx * 8, xb + (size_t)idx * 8);
  } else if (idx < 2228224) {
    const int i = idx - 2097152;
    cvt8(Wout + (size_t)i * 8, Woutb + (size_t)i * 8);
  } else {
    const int c = idx - 2228224;          // 0..393215
    const int dr = c >> 7, i = c & 127;   // packed row, chunk-in-row
    const int head = dr / 192, s = dr - head * 192;
    const int src = (s < 64) ? head * 64 + s
                  : (s < 128) ? 1024 + head * 64 + (s - 64)
                              : 2048 + head * 64 + (s - 128);
    cvt8(Win + (size_t)src * 1024 + i * 8, Wpk + (size_t)dr * 1024 + i * 8);
  }
}

// ---------------------------------------------------------------------------
// Out-projection GEMM: BM=128, BN=256, BK=32 double-buffered pipeline.
// grid(4,128)=512 blocks = exactly 2/CU (one round). LDS 2x24KB = 48KB.
// Wave tile 64x128: acc[4][8]. 6 gld_lds per stage -> vmcnt(6) steady-state.
__global__ __launch_bounds__(256, 2) void gemm_out(
    const bf16_t* __restrict__ A, const bf16_t* __restrict__ Bm,
    const float* __restrict__ bias, float* __restrict__ C,
    int M, int N, int K) {
  __shared__ __align__(16) bf16_t smem[2][128 * 32 + 256 * 32];  // 2 x 24 KB
  const int tid  = threadIdx.x;
  const int lane = tid & 63;
  const int wave = tid >> 6;
  const int n16  = lane & 15;
  const int q4   = lane >> 4;
  const int wm   = (wave >> 1) * 64;
  const int wn   = (wave & 1) * 128;
  const int m0   = blockIdx.y * 128;
  const int n0   = blockIdx.x * 256;

  floatx4 acc[4][8] = {};

#define GO_STAGE(BUF, K0)                                                   \
  {                                                                         \
    bf16_t* Ad = smem[BUF];                                                 \
    bf16_t* Bd = smem[BUF] + 128 * 32;                                      \
    _Pragma("unroll")                                                       \
    for (int it = 0; it < 2; ++it) {  /* A: 512 chunks of 8 */              \
      const int ch = it * 256 + tid;                                        \
      const int r  = ch >> 2, c8 = (ch & 3) ^ ((r >> 1) & 3);               \
      gld_lds16(A + (size_t)(m0 + r) * K + (K0) + c8 * 8,                   \
                Ad + (it * 256 + wave * 64) * 8);                           \
    }                                                                       \
    _Pragma("unroll")                                                       \
    for (int it = 0; it < 4; ++it) {  /* B: 1024 chunks of 8 */             \
      const int ch = it * 256 + tid;                                        \
      const int r  = ch >> 2, c8 = (ch & 3) ^ ((r >> 1) & 3);               \
      gld_lds16(Bm + (size_t)(n0 + r) * K + (K0) + c8 * 8,                  \
                Bd + (it * 256 + wave * 64) * 8);                           \
    }                                                                       \
  }

#define GO_ITER(T, BUF)                                                     \
  {                                                                         \
    if ((T) < 31) { asm volatile("s_waitcnt vmcnt(6)" ::: "memory"); }      \
    else          { asm volatile("s_waitcnt vmcnt(0)" ::: "memory"); }      \
    __builtin_amdgcn_s_barrier();                                           \
    __builtin_amdgcn_sched_barrier(0);                                      \
    const bf16_t* As_ = smem[BUF];                                          \
    const bf16_t* Bs_ = smem[BUF] + 128 * 32;                               \
    bf16x8 af[4], bfr[8];                                                   \
    _Pragma("unroll")                                                       \
    for (int i = 0; i < 4; ++i) {                                           \
      const int row = wm + i * 16 + n16;                                    \
      af[i] = *(const bf16x8*)&As_[row * 32 + ((q4 ^ ((row >> 1) & 3)) * 8)]; \
    }                                                                       \
    _Pragma("unroll")                                                       \
    for (int j = 0; j < 8; ++j) {                                           \
      const int row = wn + j * 16 + n16;                                    \
      bfr[j] = *(const bf16x8*)&Bs_[row * 32 + ((q4 ^ ((row >> 1) & 3)) * 8)]; \
    }                                                                       \
    __builtin_amdgcn_s_setprio(1);                                          \
    _Pragma("unroll")                                                       \
    for (int i = 0; i < 4; ++i)                                             \
      _Pragma("unroll")                                                     \
      for (int j = 0; j < 8; ++j)                                           \
        acc[i][j] = MFMA_16x16x32(af[i], bfr[j], acc[i][j]);                \
    __builtin_amdgcn_s_setprio(0);                                          \
    asm volatile("s_waitcnt lgkmcnt(0)" ::: "memory");                      \
    __builtin_amdgcn_s_barrier();                                           \
    __builtin_amdgcn_sched_barrier(0);                                      \
    if ((T) + 2 < 32) GO_STAGE(BUF, ((T) + 2) * 32)                         \
  }

  GO_STAGE(0, 0)
  GO_STAGE(1, 32)
  for (int t = 0; t < 32; t += 2) {
    GO_ITER(t, 0)
    GO_ITER(t + 1, 1)
  }
#undef GO_ITER
#undef GO_STAGE

#pragma unroll
  for (int i = 0; i < 4; ++i)
#pragma unroll
    for (int j = 0; j < 8; ++j) {
      const int col = n0 + wn + j * 16 + n16;
      const float b = bias[col];
#pragma unroll
      for (int r = 0; r < 4; ++r) {
        const int row = m0 + wm + i * 16 + q4 * 4 + r;
        C[(size_t)row * N + col] = acc[i][j][r] + b;
      }
    }
}

// ---------------------------------------------------------------------------
// Fused QKV-projection + windowed attention.
// Phase 1: BK=32 double-buffered counted-vmcnt pipeline (conflict-free
// swizzle); staging dbuf [0,40960B) aliases the attention region, total LDS
// 53248 B -> 3 blocks/CU. 5 gld_lds per stage -> vmcnt(5) steady-state.
// Phase 2 (S=qk^T, softmax, PV) unchanged.
__global__ __launch_bounds__(256, 3) void qkv_attn(
    const bf16_t* __restrict__ X,    // [16384,1024]
    const bf16_t* __restrict__ Wpk,  // [16][192][1024]
    const float* __restrict__ bin,   // [3072]
    bf16_t* __restrict__ o)          // [16384,1024] merged heads
{
  __shared__ __align__(16) bf16_t smem[26624];  // 53248 B
  // staging: buf b at smem + b*10240: Xs [128][32] (4096), Ws [192][32] (6144)
  bf16_t* qs  = smem;                // [128][72] (aliases staging, post-barrier)
  bf16_t* ks  = smem + 9216;         // [128][72]
  bf16_t* vsT = smem + 18432;        // [64][128] XOR-swizzled
  bf16_t* Ps  = smem;                // [128][136] = 17408 <= 18432 (qs+ks)

  const int wid  = blockIdx.x;       // window 0..127 (XCD-affine: wid%8)
  const int h    = blockIdx.y;       // head 0..15
  const int tid  = threadIdx.x;
  const int lane = tid & 63;
  const int wave = tid >> 6;
  const int n16  = lane & 15;
  const int q4   = lane >> 4;
  const int wm   = (wave >> 1) * 64;   // wave M-offset (0/64)
  const int wn   = (wave & 1) * 96;    // wave N-offset (0/96)

  const bf16_t* Xg = X + (size_t)wid * 128 * 1024;
  const bf16_t* Wg = Wpk + (size_t)h * 192 * 1024;

  // ---- phase 1: qkv = x @ W^T   (M=128, N=192, K=1024, BK=32, dbuf pipeline)
  floatx4 acc[4][6] = {};

#define QKV_STAGE(BUF, K0)                                                  \
  {                                                                         \
    bf16_t* Xd = smem + (BUF) * 10240;                                      \
    bf16_t* Wd = Xd + 4096;                                                 \
    _Pragma("unroll")                                                       \
    for (int it = 0; it < 2; ++it) {  /* X: 512 chunks of 8 */              \
      const int ch = it * 256 + tid;                                        \
      const int r  = ch >> 2, c8 = (ch & 3) ^ ((r >> 1) & 3);               \
      gld_lds16(Xg + (size_t)r * 1024 + (K0) + c8 * 8,                      \
                Xd + (it * 256 + wave * 64) * 8);                           \
    }                                                                       \
    _Pragma("unroll")                                                       \
    for (int it = 0; it < 3; ++it) {  /* W: 768 chunks of 8 */              \
      const int ch = it * 256 + tid;                                        \
      const int r  = ch >> 2, c8 = (ch & 3) ^ ((r >> 1) & 3);               \
      gld_lds16(Wg + (size_t)r * 1024 + (K0) + c8 * 8,                      \
                Wd + (it * 256 + wave * 64) * 8);                           \
    }                                                                       \
  }

#define QKV_ITER(T, BUF)                                                    \
  {                                                                         \
    if ((T) < 31) { asm volatile("s_waitcnt vmcnt(5)" ::: "memory"); }      \
    else          { asm volatile("s_waitcnt vmcnt(0)" ::: "memory"); }      \
    __builtin_amdgcn_s_barrier();                                           \
    __builtin_amdgcn_sched_barrier(0);                                      \
    const bf16_t* Xb = smem + (BUF) * 10240;                                \
    const bf16_t* Wb = Xb + 4096;                                           \
    bf16x8 af[4], bfr[6];                                                   \
    _Pragma("unroll")                                                       \
    for (int i = 0; i < 4; ++i) {                                           \
      const int row = wm + i * 16 + n16;                                    \
      af[i] = *(const bf16x8*)&Xb[row * 32 + ((q4 ^ ((row >> 1) & 3)) * 8)]; \
    }                                                                       \
    _Pragma("unroll")                                                       \
    for (int j = 0; j < 6; ++j) {                                           \
      const int row = wn + j * 16 + n16;                                    \
      bfr[j] = *(const bf16x8*)&Wb[row * 32 + ((q4 ^ ((row >> 1) & 3)) * 8)]; \
    }                                                                       \
    __builtin_amdgcn_s_setprio(1);                                          \
    _Pragma("unroll")                                                       \
    for (int i = 0; i < 4; ++i)                                             \
      _Pragma("unroll")                                                     \
      for (int j = 0; j < 6; ++j)                                           \
        acc[i][j] = MFMA_16x16x32(af[i], bfr[j], acc[i][j]);                \
    __builtin_amdgcn_s_setprio(0);                                          \
    asm volatile("s_waitcnt lgkmcnt(0)" ::: "memory");                      \
    __builtin_amdgcn_s_barrier();                                           \
    __builtin_amdgcn_sched_barrier(0);                                      \
    if ((T) + 2 < 32) QKV_STAGE(BUF, ((T) + 2) * 32)                        \
  }

  QKV_STAGE(0, 0)
  QKV_STAGE(1, 32)
  for (int t = 0; t < 32; t += 2) {
    QKV_ITER(t, 0)
    QKV_ITER(t + 1, 1)
  }
#undef QKV_ITER
#undef QKV_STAGE
  // final in-loop barrier: staging dead, all reads done -> qs/ks/vsT may alias

  // ---- epilogue: scatter acc -> qs (scaled), ks, vsT (swizzled transpose)
#pragma unroll
  for (int j = 0; j < 6; ++j) {
    const int base = wn + j * 16;   // wave-uniform
    const int col  = base + n16;    // 0..191
    const int gb = (base < 64) ? h * 64 + col
                 : (base < 128) ? 1024 + h * 64 + (col - 64)
                                : 2048 + h * 64 + (col - 128);
    const float bias = bin[gb];
#pragma unroll
    for (int i = 0; i < 4; ++i) {
      const int row0 = wm + i * 16 + q4 * 4;
      if (base < 64) {        // q, fold softmax scale 1/sqrt(64)
#pragma unroll
        for (int r = 0; r < 4; ++r)
          qs[(row0 + r) * 72 + col] = (bf16_t)((acc[i][j][r] + bias) * 0.125f);
      } else if (base < 128) {  // k
#pragma unroll
        for (int r = 0; r < 4; ++r)
          ks[(row0 + r) * 72 + (col - 64)] = (bf16_t)(acc[i][j][r] + bias);
      } else {                  // v -> transposed [dim][token], swizzled
        bf16x4 pv;
#pragma unroll
        for (int r = 0; r < 4; ++r) pv[r] = (bf16_t)(acc[i][j][r] + bias);
        const int d = col - 128;          // dim 0..63; d&15 == n16
        const int c8 = row0 >> 3, pos = row0 & 7;
        *(bf16x4*)&vsT[d * 128 + ((c8 ^ n16) << 3) + pos] = pv;
      }
    }
  }
  __syncthreads();

  // ---- S = q k^T  (wave w owns S rows [32w, 32w+32), K=64)
  floatx4 sacc[2][8] = {};
#pragma unroll
  for (int ks0 = 0; ks0 < 2; ++ks0) {
    bf16x8 aq[2];
#pragma unroll
    for (int i = 0; i < 2; ++i)
      aq[i] = *(const bf16x8*)&qs[(wave * 32 + i * 16 + n16) * 72 + ks0 * 32 + q4 * 8];
#pragma unroll
    for (int j = 0; j < 8; ++j) {
      bf16x8 bk = *(const bf16x8*)&ks[(j * 16 + n16) * 72 + ks0 * 32 + q4 * 8];
      sacc[0][j] = MFMA_16x16x32(aq[0], bk, sacc[0][j]);
      sacc[1][j] = MFMA_16x16x32(aq[1], bk, sacc[1][j]);
    }
  }
  __syncthreads();  // q/k reads done; Ps may overwrite their LDS

  // ---- softmax: no max-sub (logits bounded), P unnormalized, defer 1/sum
  float invs[2][4];
#pragma unroll
  for (int i = 0; i < 2; ++i) {
#pragma unroll
    for (int r = 0; r < 4; ++r) {
      float vals[8];
      float s = 0.f;
#pragma unroll
      for (int j = 0; j < 8; ++j) {
        vals[j] = __expf(sacc[i][j][r]);
        s += vals[j];
      }
      for (int m = 1; m < 16; m <<= 1) s += __shfl_xor(s, m, 64);
      invs[i][r] = 1.0f / s;
      const int prow = wave * 32 + i * 16 + q4 * 4 + r;
#pragma unroll
      for (int j = 0; j < 8; ++j)
        Ps[prow * 136 + j * 16 + n16] = (bf16_t)vals[j];
    }
  }
  __syncthreads();

  // ---- O = P V  (K=128; both operands via ds_read_b128)
  floatx4 oacc[2][4] = {};
#pragma unroll
  for (int kk = 0; kk < 4; ++kk) {
    bf16x8 ap[2];
#pragma unroll
    for (int i = 0; i < 2; ++i)
      ap[i] = *(const bf16x8*)&Ps[(wave * 32 + i * 16 + n16) * 136 + kk * 32 + q4 * 8];
#pragma unroll
    for (int j = 0; j < 4; ++j) {
      const int d = j * 16 + n16;
      bf16x8 bv = *(const bf16x8*)&vsT[d * 128 + (((kk * 4 + q4) ^ n16) << 3)];
      oacc[0][j] = MFMA_16x16x32(ap[0], bv, oacc[0][j]);
      oacc[1][j] = MFMA_16x16x32(ap[1], bv, oacc[1][j]);
    }
  }

  // ---- write o slice (scaled by 1/rowsum), merged-head layout [tok][h*64+d]
  bf16_t* go = o + (size_t)wid * 128 * 1024 + h * 64;
#pragma unroll
  for (int i = 0; i < 2; ++i)
#pragma unroll
    for (int j = 0; j < 4; ++j)
#pragma unroll
      for (int r = 0; r < 4; ++r) {
        const int row = wave * 32 + i * 16 + q4 * 4 + r;
        go[(size_t)row * 1024 + j * 16 + n16] = (bf16_t)(oacc[i][j][r] * invs[i][r]);
      }
}

// ---------------------------------------------------------------------------
extern "C" void kernel_launch(void* const* d_in, const int* in_sizes, int n_in,
                              void* d_out, int out_size, void* d_ws, size_t ws_size,
                              hipStream_t stream) {
  const float* x    = (const float*)d_in[0];
  const float* Win  = (const float*)d_in[1];   // [3072,1024]
  const float* bin  = (const float*)d_in[2];   // [3072]
  const float* Wout = (const float*)d_in[3];   // [1024,1024]
  const float* bout = (const float*)d_in[4];   // [1024]
  float* out = (float*)d_out;

  const size_t M = 16384, H = 1024, H3 = 3072;

  // workspace layout (~72 MB): xb | Wpk | Woutb | ob
  bf16_t* xb    = (bf16_t*)d_ws;        // M*H
  bf16_t* Wpk   = xb + M * H;           // H3*H (head-packed)
  bf16_t* Woutb = Wpk + H3 * H;         // H*H
  bf16_t* ob    = Woutb + H * H;        // M*H

  // one fused conversion dispatch: 2,621,440 8-elem chunks / 256 = 10240 blocks
  cvt_all<<<dim3(10240), 256, 0, stream>>>(x, Win, Wout, xb, Wpk, Woutb);

  // grid: window-major -> linear id = wid + 128*h -> window pins to XCD wid%8,
  // all 16 heads of a window share that XCD's L2 copy of X.
  qkv_attn<<<dim3(128, 16), 256, 0, stream>>>(xb, Wpk, bin, ob);

  // 512 blocks = one full dispatch round at 2/CU; XCD id%8 pins one B-tile.
  gemm_out<<<dim3((unsigned)(H / 256), (unsigned)(M / 128)), 256, 0, stream>>>(
      ob, Woutb, bout, out, (int)M, (int)H, (int)H);
}

// Round 3
// 289.070 us; speedup vs baseline: 1.0240x; 1.0067x over previous
//
#include <hip/hip_runtime.h>
#include <hip/hip_bf16.h>
#include <cstdint>

// ---------------------------------------------------------------------------
// LocalWindowTransformer: windowed MHA, B=4 L=4096 H=1024 NH=16 hd=64 P=128
// R8: post-mortem of R6/R7 — counted-vmcnt pipeline on a 2-phase structure
//     is null-to-negative (reproduces guide m131/m139); qkv reverted to the
//     R5 drain-0 BK=64 structure (965 TF effective, 43.6% MfmaUtil).
//     gemm_out's real problem is occupancy, not pipelining: 512 blocks =
//     2/CU = 8 waves/CU cannot hide the drain stall. -> BN 256->128:
//     grid(8,128)=1024 blocks = 4 blocks/CU (16 waves/CU), 32KB LDS,
//     exact m97 wave-tile (64x64, acc[4][4], 32 MFMA / 16 ds_read per
//     K-step). XCD id%8 = x pins one 256KB B-column per XCD.
// MFMA 16x16x32 bf16 layouts (HW-verified per guide):
//   A-frag: lane holds A[m=lane&15][k=(lane>>4)*8+j], j=0..7
//   B-frag: lane holds B_hw[k=(lane>>4)*8+j][n=lane&15]
//   C/D   : reg r holds C[row=(lane>>4)*4+r][col=lane&15]
// Swizzled staging (BK=64): LDS row r (64 elems) holds global chunk kc at
//   position (kc ^ (r&7)); fragment read addr = r*64 + (((half*4+q4)^(r&7))*8).
// ---------------------------------------------------------------------------

typedef __bf16 bf16_t;
typedef __bf16 bf16x8 __attribute__((ext_vector_type(8)));
typedef __bf16 bf16x4 __attribute__((ext_vector_type(4)));
typedef float  floatx4 __attribute__((ext_vector_type(4)));

#define MFMA_16x16x32(A, B, C) __builtin_amdgcn_mfma_f32_16x16x32_bf16(A, B, C, 0, 0, 0)

// async global->LDS, 16B per lane; LDS dest = wave-uniform base + lane*16
__device__ __forceinline__ void gld_lds16(const bf16_t* g, bf16_t* l) {
  __builtin_amdgcn_global_load_lds(
      (__attribute__((address_space(1))) void*)(void*)(g),
      (__attribute__((address_space(3))) void*)(l), 16, 0, 0);
}

__device__ __forceinline__ void cvt8(const float* __restrict__ s,
                                     bf16_t* __restrict__ d) {
  float4 a = ((const float4*)s)[0];
  float4 b = ((const float4*)s)[1];
  bf16x8 o;
  o[0] = (bf16_t)a.x; o[1] = (bf16_t)a.y; o[2] = (bf16_t)a.z; o[3] = (bf16_t)a.w;
  o[4] = (bf16_t)b.x; o[5] = (bf16_t)b.y; o[6] = (bf16_t)b.z; o[7] = (bf16_t)b.w;
  *(bf16x8*)d = o;
}

// ---------------------------------------------------------------------------
// One fused conversion dispatch, 8-elem chunks:
//   [0, 2097152)              x    [16384,1024] -> xb
//   [2097152, 2228224)        Wout [1024,1024]  -> Woutb
//   [2228224, 2621440)        Win  [3072,1024]  -> Wpk (head-packed repack)
__global__ void cvt_all(const float* __restrict__ x,
                        const float* __restrict__ Win,
                        const float* __restrict__ Wout,
                        bf16_t* __restrict__ xb,
                        bf16_t* __restrict__ Wpk,
                        bf16_t* __restrict__ Woutb) {
  const int idx = blockIdx.x * 256 + threadIdx.x;
  if (idx < 2097152) {
    cvt8(x + (size_t)idx * 8, xb + (size_t)idx * 8);
  } else if (idx < 2228224) {
    const int i = idx - 2097152;
    cvt8(Wout + (size_t)i * 8, Woutb + (size_t)i * 8);
  } else {
    const int c = idx - 2228224;          // 0..393215
    const int dr = c >> 7, i = c & 127;   // packed row, chunk-in-row
    const int head = dr / 192, s = dr - head * 192;
    const int src = (s < 64) ? head * 64 + s
                  : (s < 128) ? 1024 + head * 64 + (s - 64)
                              : 2048 + head * 64 + (s - 128);
    cvt8(Win + (size_t)src * 1024 + i * 8, Wpk + (size_t)dr * 1024 + i * 8);
  }
}

// ---------------------------------------------------------------------------
// Out-projection GEMM: BM=128, BN=128, BK=64, m97 structure (drain-0).
// grid(8,128)=1024 blocks = 4 blocks/CU (16 waves/CU) -> TLP hides the
// barrier drain. LDS 32KB. Wave tile 64x64: acc[4][4], 32 MFMA / 16
// ds_read_b128 per K-step. XCD id%8 = blockIdx.x pins one B-column/XCD.
__global__ __launch_bounds__(256, 4) void gemm_out(
    const bf16_t* __restrict__ A, const bf16_t* __restrict__ Bm,
    const float* __restrict__ bias, float* __restrict__ C,
    int M, int N, int K) {
  __shared__ bf16_t As[128 * 64];   // 16 KB
  __shared__ bf16_t Bs[128 * 64];   // 16 KB
  const int tid  = threadIdx.x;
  const int lane = tid & 63;
  const int wave = tid >> 6;
  const int n16  = lane & 15;
  const int q4   = lane >> 4;
  const int wm   = (wave >> 1) * 64;
  const int wn   = (wave & 1) * 64;
  const int m0   = blockIdx.y * 128;
  const int n0   = blockIdx.x * 128;

  floatx4 acc[4][4] = {};

  for (int k0 = 0; k0 < K; k0 += 64) {
    __syncthreads();
#pragma unroll
    for (int it = 0; it < 4; ++it) {       // As: 1024 chunks of 8
      const int ch = it * 256 + tid;
      const int r  = ch >> 3;
      const int c8 = (ch & 7) ^ (r & 7);
      gld_lds16(A + (size_t)(m0 + r) * K + k0 + c8 * 8,
                As + (it * 256 + wave * 64) * 8);
    }
#pragma unroll
    for (int it = 0; it < 4; ++it) {       // Bs: 1024 chunks of 8
      const int ch = it * 256 + tid;
      const int r  = ch >> 3;
      const int c8 = (ch & 7) ^ (r & 7);
      gld_lds16(Bm + (size_t)(n0 + r) * K + k0 + c8 * 8,
                Bs + (it * 256 + wave * 64) * 8);
    }
    __syncthreads();

#pragma unroll
    for (int half = 0; half < 2; ++half) {
      bf16x8 af[4], bfr[4];
#pragma unroll
      for (int i = 0; i < 4; ++i) {
        const int row = wm + i * 16 + n16;
        af[i] = *(const bf16x8*)&As[row * 64 + (((half * 4 + q4) ^ (row & 7)) * 8)];
      }
#pragma unroll
      for (int j = 0; j < 4; ++j) {
        const int row = wn + j * 16 + n16;
        bfr[j] = *(const bf16x8*)&Bs[row * 64 + (((half * 4 + q4) ^ (row & 7)) * 8)];
      }
#pragma unroll
      for (int i = 0; i < 4; ++i)
#pragma unroll
        for (int j = 0; j < 4; ++j)
          acc[i][j] = MFMA_16x16x32(af[i], bfr[j], acc[i][j]);
    }
  }

#pragma unroll
  for (int i = 0; i < 4; ++i)
#pragma unroll
    for (int j = 0; j < 4; ++j) {
      const int col = n0 + wn + j * 16 + n16;
      const float b = bias[col];
#pragma unroll
      for (int r = 0; r < 4; ++r) {
        const int row = m0 + wm + i * 16 + q4 * 4 + r;
        C[(size_t)row * N + col] = acc[i][j][r] + b;
      }
    }
}

// ---------------------------------------------------------------------------
// Fused QKV-projection + windowed attention (R5 structure, verified fastest).
// One 256-thread block per (window, head). Phase 1: qkv[128,192] =
// x_win[128,1024] @ Wpk_h^T, BK=64 swizzled staging, drain-0 2-barrier loop
// (3 blocks/CU of heterogeneous waves hide the drain; counted-vmcnt variant
// measured SLOWER, R6/R7). Epilogue scatters acc into LDS: q (scaled 1/8,
// [128][72]), k ([128][72]), V transposed into XOR-swizzled [64][128].
// Phase 2: S=q k^T; softmax with no max-sub (logits bounded), P unnormalized,
// 1/sum folded into O. LDS 53248 B -> 3 blocks/CU.
__global__ __launch_bounds__(256, 3) void qkv_attn(
    const bf16_t* __restrict__ X,    // [16384,1024]
    const bf16_t* __restrict__ Wpk,  // [16][192][1024]
    const float* __restrict__ bin,   // [3072]
    bf16_t* __restrict__ o)          // [16384,1024] merged heads
{
  __shared__ bf16_t smem[26624];     // 53248 B
  bf16_t* Xs  = smem;                // [128][64] staging (phase 1 only)
  bf16_t* Ws  = smem + 8192;         // [192][64] staging (ends 20480)
  bf16_t* qs  = smem;                // [128][72] (aliases staging, post-barrier)
  bf16_t* ks  = smem + 9216;         // [128][72]
  bf16_t* vsT = smem + 18432;        // [64][128] XOR-swizzled
  bf16_t* Ps  = smem;                // [128][136] = 17408 <= 18432 (qs+ks)

  const int wid  = blockIdx.x;       // window 0..127 (XCD-affine: wid%8)
  const int h    = blockIdx.y;       // head 0..15
  const int tid  = threadIdx.x;
  const int lane = tid & 63;
  const int wave = tid >> 6;
  const int n16  = lane & 15;
  const int q4   = lane >> 4;
  const int wm   = (wave >> 1) * 64;   // wave M-offset (0/64)
  const int wn   = (wave & 1) * 96;    // wave N-offset (0/96)

  const bf16_t* Xg = X + (size_t)wid * 128 * 1024;
  const bf16_t* Wg = Wpk + (size_t)h * 192 * 1024;

  // ---- phase 1: qkv = x @ W^T   (M=128, N=192, K=1024, BK=64)
  floatx4 acc[4][6] = {};
  for (int k0 = 0; k0 < 1024; k0 += 64) {
    __syncthreads();
#pragma unroll
    for (int it = 0; it < 4; ++it) {  // X: 1024 chunks of 8
      const int ch = it * 256 + tid;
      const int r  = ch >> 3;
      const int c8 = (ch & 7) ^ (r & 7);
      gld_lds16(Xg + (size_t)r * 1024 + k0 + c8 * 8,
                Xs + (it * 256 + wave * 64) * 8);
    }
#pragma unroll
    for (int it = 0; it < 6; ++it) {  // W: 1536 chunks of 8
      const int ch = it * 256 + tid;
      const int r  = ch >> 3;
      const int c8 = (ch & 7) ^ (r & 7);
      gld_lds16(Wg + (size_t)r * 1024 + k0 + c8 * 8,
                Ws + (it * 256 + wave * 64) * 8);
    }
    __syncthreads();

#pragma unroll
    for (int half = 0; half < 2; ++half) {
      bf16x8 af[4], bfr[6];
#pragma unroll
      for (int i = 0; i < 4; ++i) {
        const int row = wm + i * 16 + n16;
        af[i] = *(const bf16x8*)&Xs[row * 64 + (((half * 4 + q4) ^ (row & 7)) * 8)];
      }
#pragma unroll
      for (int j = 0; j < 6; ++j) {
        const int row = wn + j * 16 + n16;
        bfr[j] = *(const bf16x8*)&Ws[row * 64 + (((half * 4 + q4) ^ (row & 7)) * 8)];
      }
#pragma unroll
      for (int i = 0; i < 4; ++i)
#pragma unroll
        for (int j = 0; j < 6; ++j)
          acc[i][j] = MFMA_16x16x32(af[i], bfr[j], acc[i][j]);
    }
  }
  __syncthreads();  // staging region dead -> qs/ks/vsT may alias it

  // ---- epilogue: scatter acc -> qs (scaled), ks, vsT (swizzled transpose)
#pragma unroll
  for (int j = 0; j < 6; ++j) {
    const int base = wn + j * 16;   // wave-uniform
    const int col  = base + n16;    // 0..191
    const int gb = (base < 64) ? h * 64 + col
                 : (base < 128) ? 1024 + h * 64 + (col - 64)
                                : 2048 + h * 64 + (col - 128);
    const float bias = bin[gb];
#pragma unroll
    for (int i = 0; i < 4; ++i) {
      const int row0 = wm + i * 16 + q4 * 4;
      if (base < 64) {        // q, fold softmax scale 1/sqrt(64)
#pragma unroll
        for (int r = 0; r < 4; ++r)
          qs[(row0 + r) * 72 + col] = (bf16_t)((acc[i][j][r] + bias) * 0.125f);
      } else if (base < 128) {  // k
#pragma unroll
        for (int r = 0; r < 4; ++r)
          ks[(row0 + r) * 72 + (col - 64)] = (bf16_t)(acc[i][j][r] + bias);
      } else {                  // v -> transposed [dim][token], swizzled
        bf16x4 pv;
#pragma unroll
        for (int r = 0; r < 4; ++r) pv[r] = (bf16_t)(acc[i][j][r] + bias);
        const int d = col - 128;          // dim 0..63; d&15 == n16
        const int c8 = row0 >> 3, pos = row0 & 7;
        *(bf16x4*)&vsT[d * 128 + ((c8 ^ n16) << 3) + pos] = pv;
      }
    }
  }
  __syncthreads();

  // ---- S = q k^T  (wave w owns S rows [32w, 32w+32), K=64)
  floatx4 sacc[2][8] = {};
#pragma unroll
  for (int ks0 = 0; ks0 < 2; ++ks0) {
    bf16x8 aq[2];
#pragma unroll
    for (int i = 0; i < 2; ++i)
      aq[i] = *(const bf16x8*)&qs[(wave * 32 + i * 16 + n16) * 72 + ks0 * 32 + q4 * 8];
#pragma unroll
    for (int j = 0; j < 8; ++j) {
      bf16x8 bk = *(const bf16x8*)&ks[(j * 16 + n16) * 72 + ks0 * 32 + q4 * 8];
      sacc[0][j] = MFMA_16x16x32(aq[0], bk, sacc[0][j]);
      sacc[1][j] = MFMA_16x16x32(aq[1], bk, sacc[1][j]);
    }
  }
  __syncthreads();  // q/k reads done; Ps may overwrite their LDS

  // ---- softmax: no max-sub (logits bounded), P unnormalized, defer 1/sum
  float invs[2][4];
#pragma unroll
  for (int i = 0; i < 2; ++i) {
#pragma unroll
    for (int r = 0; r < 4; ++r) {
      float vals[8];
      float s = 0.f;
#pragma unroll
      for (int j = 0; j < 8; ++j) {
        vals[j] = __expf(sacc[i][j][r]);
        s += vals[j];
      }
      for (int m = 1; m < 16; m <<= 1) s += __shfl_xor(s, m, 64);
      invs[i][r] = 1.0f / s;
      const int prow = wave * 32 + i * 16 + q4 * 4 + r;
#pragma unroll
      for (int j = 0; j < 8; ++j)
        Ps[prow * 136 + j * 16 + n16] = (bf16_t)vals[j];
    }
  }
  __syncthreads();

  // ---- O = P V  (K=128; both operands via ds_read_b128)
  floatx4 oacc[2][4] = {};
#pragma unroll
  for (int kk = 0; kk < 4; ++kk) {
    bf16x8 ap[2];
#pragma unroll
    for (int i = 0; i < 2; ++i)
      ap[i] = *(const bf16x8*)&Ps[(wave * 32 + i * 16 + n16) * 136 + kk * 32 + q4 * 8];
#pragma unroll
    for (int j = 0; j < 4; ++j) {
      const int d = j * 16 + n16;
      bf16x8 bv = *(const bf16x8*)&vsT[d * 128 + (((kk * 4 + q4) ^ n16) << 3)];
      oacc[0][j] = MFMA_16x16x32(ap[0], bv, oacc[0][j]);
      oacc[1][j] = MFMA_16x16x32(ap[1], bv, oacc[1][j]);
    }
  }

  // ---- write o slice (scaled by 1/rowsum), merged-head layout [tok][h*64+d]
  bf16_t* go = o + (size_t)wid * 128 * 1024 + h * 64;
#pragma unroll
  for (int i = 0; i < 2; ++i)
#pragma unroll
    for (int j = 0; j < 4; ++j)
#pragma unroll
      for (int r = 0; r < 4; ++r) {
        const int row = wave * 32 + i * 16 + q4 * 4 + r;
        go[(size_t)row * 1024 + j * 16 + n16] = (bf16_t)(oacc[i][j][r] * invs[i][r]);
      }
}

// ---------------------------------------------------------------------------
extern "C" void kernel_launch(void* const* d_in, const int* in_sizes, int n_in,
                              void* d_out, int out_size, void* d_ws, size_t ws_size,
                              hipStream_t stream) {
  const float* x    = (const float*)d_in[0];
  const float* Win  = (const float*)d_in[1];   // [3072,1024]
  const float* bin  = (const float*)d_in[2];   // [3072]
  const float* Wout = (const float*)d_in[3];   // [1024,1024]
  const float* bout = (const float*)d_in[4];   // [1024]
  float* out = (float*)d_out;

  const size_t M = 16384, H = 1024, H3 = 3072;

  // workspace layout (~72 MB): xb | Wpk | Woutb | ob
  bf16_t* xb    = (bf16_t*)d_ws;        // M*H
  bf16_t* Wpk   = xb + M * H;           // H3*H (head-packed)
  bf16_t* Woutb = Wpk + H3 * H;         // H*H
  bf16_t* ob    = Woutb + H * H;        // M*H

  // one fused conversion dispatch: 2,621,440 8-elem chunks / 256 = 10240 blocks
  cvt_all<<<dim3(10240), 256, 0, stream>>>(x, Win, Wout, xb, Wpk, Woutb);

  // grid: window-major -> linear id = wid + 128*h -> window pins to XCD wid%8,
  // all 16 heads of a window share that XCD's L2 copy of X.
  qkv_attn<<<dim3(128, 16), 256, 0, stream>>>(xb, Wpk, bin, ob);

  // 1024 blocks = 4/CU; XCD id%8 = x pins one 256KB B-column per XCD.
  gemm_out<<<dim3((unsigned)(H / 128), (unsigned)(M / 128)), 256, 0, stream>>>(
      ob, Woutb, bout, out, (int)M, (int)H, (int)H);
}